// Round 14
// baseline (409.755 us; speedup 1.0000x reference)
//
#include <hip/hip_runtime.h>
#include <hip/hip_cooperative_groups.h>

namespace cg = cooperative_groups;

using u16 = unsigned short;
using u32 = unsigned int;

typedef __bf16 bf16x8 __attribute__((ext_vector_type(8)));
typedef float f32x4 __attribute__((ext_vector_type(4)));

#define T_SEQ 2048
#define NC 1024
#define HDIM 64
#define WINSZ 256
#define QSTEP (2.0f / 255.0f)

__device__ __forceinline__ float b2f(u16 u) {
  u32 v = ((u32)u) << 16;
  return __builtin_bit_cast(float, v);
}
__device__ __forceinline__ u16 f2b(float f) {
  u32 x = __builtin_bit_cast(u32, f);
  u32 r = (x + 0x7fffu + ((x >> 16) & 1u)) >> 16;  // RNE
  return (u16)r;
}
__device__ __forceinline__ float quantize(float v) {
  v = fminf(fmaxf(v, -1.0f), 1.0f);
  return QSTEP * rintf(v / QSTEP);
}

// ============ fused pipeline: one cooperative launch (768 blocks = 3/CU), 3 grid syncs ====
// R14: R13's 1024-block version never launched (output all-zero => launch error; 4/CU
// co-residency too tight). 768 blocks = 3/CU with bounds(256,3) gives VGPR/LDS slack.
// P2's 1024 attn tiles are grid-strided. Host checks the return code and falls back to
// the verified 4-kernel path on failure.
__global__ __launch_bounds__(256, 3) void fused(
    const float* __restrict__ xf, u16* __restrict__ xb,
    const float* __restrict__ wa, u16* __restrict__ wTa,
    const float* __restrict__ wp, u16* __restrict__ wTp,
    u16* __restrict__ qh, u16* __restrict__ kh, u16* __restrict__ vt,
    u16* __restrict__ yq, float* __restrict__ out) {
  cg::grid_group grid = cg::this_grid();
  __shared__ __align__(16) union {
    struct { u16 As[4096]; u16 Bs[8192]; } g2;       // P1 single-buf: 24 KB
    struct { u16 S[32 * 328]; float Linv[32]; } at;  // P2: 21 KB
    struct { u16 As[4096]; u16 Bs[4096]; } g4;       // P3 single-buf: 16 KB
    u16 tile[64][65];                                // P0 transpose: 8.3 KB
  } sh;

  const int b = blockIdx.x;
  const int tid = threadIdx.x;
  const int lane = tid & 63;
  const int wave = tid >> 6;
  const int ln15 = lane & 15, lq = lane >> 4;
  const int l7 = ln15 & 7;

  // ---------------- P0: x convert + both transposes (1024 tile-jobs over 768 blocks) ----
  {
    const int n4 = T_SEQ * NC / 4;
    for (int i = b * 256 + tid; i < n4; i += 768 * 256) {
      const float4 v = ((const float4*)xf)[i];
      ushort4 o;
      o.x = f2b(v.x); o.y = f2b(v.y); o.z = f2b(v.z); o.w = f2b(v.w);
      ((ushort4*)xb)[i] = o;
    }
    for (int j = b; j < 1024; j += 768) {
      __syncthreads();  // prior iteration's tile reads done before overwrite
      const int iswp = (j >= 768);
      const int bi = iswp ? (j - 768) : j;  // wa: 768 tiles, wp: 256 tiles
      const float* in = iswp ? wp : wa;
      u16* outw = iswp ? wTp : wTa;
      const int Cc = iswp ? 1024 : 3072;
      const int W = iswp ? 16 : 48;
      const int tc = (bi % W) * 64, tr = (bi / W) * 64;
      const int lx = tid & 63, ly = tid >> 6;
#pragma unroll
      for (int r = ly; r < 64; r += 4)
        sh.tile[r][lx] = f2b(in[(long)(tr + r) * Cc + tc + lx]);
      __syncthreads();
      const int e = tid & 31;
      const int r0 = (tid >> 5) & 1;
#pragma unroll
      for (int it = 0; it < 8; it++) {
        const int r = it * 8 + wave * 2 + r0;
        ushort2 o2;
        o2.x = sh.tile[2 * e][r];
        o2.y = sh.tile[2 * e + 1][r];
        *(ushort2*)&outw[(tc + r) * 1024 + tr + 2 * e] = o2;
      }
    }
  }
  grid.sync();

  // ---------------- P1: qkv GEMM (64x128 tile, BK=64, single-buf; 768 tiles exact) ------
  {
    const int wr = wave >> 1, wc = wave & 1;
    const int xcd = b & 7, tt = b >> 3;      // XCD rectangle (bijective, 768)
    const int bx = (xcd & 1) * 12 + tt % 12;
    const int by = (xcd >> 1) * 8 + tt / 12;
    const int m0 = by * 64, n0 = bx * 128;

    const int crow = tid >> 3, csl = tid & 7;
    const u16* ag0 = xb + (m0 + crow) * NC + csl * 8;
    const u16* bg0 = wTa + (n0 + crow) * NC + csl * 8;
    const int wofs = crow * 64 + (csl ^ (crow & 7)) * 8;

    uint4 pa0, pa1, pb0, pb1, pb2, pb3;
    f32x4 acc[2][4] = {};

#define K2_LOAD(KT)                                 \
  {                                                 \
    pa0 = *(const uint4*)(ag0 + (KT));              \
    pa1 = *(const uint4*)(ag0 + 32 * NC + (KT));    \
    pb0 = *(const uint4*)(bg0 + (KT));              \
    pb1 = *(const uint4*)(bg0 + 32 * NC + (KT));    \
    pb2 = *(const uint4*)(bg0 + 64 * NC + (KT));    \
    pb3 = *(const uint4*)(bg0 + 96 * NC + (KT));    \
  }
#define K2_WRITE()                                  \
  {                                                 \
    *(uint4*)&sh.g2.As[wofs] = pa0;                 \
    *(uint4*)&sh.g2.As[wofs + 2048] = pa1;          \
    *(uint4*)&sh.g2.Bs[wofs] = pb0;                 \
    *(uint4*)&sh.g2.Bs[wofs + 2048] = pb1;          \
    *(uint4*)&sh.g2.Bs[wofs + 4096] = pb2;          \
    *(uint4*)&sh.g2.Bs[wofs + 6144] = pb3;          \
  }

    __syncthreads();  // P0 LDS reads complete before union reuse
    K2_LOAD(0);
    K2_WRITE();
    __syncthreads();

    for (int kt = 0; kt < NC; kt += 64) {
      if (kt + 64 < NC) K2_LOAD(kt + 64);
#pragma unroll
      for (int s = 0; s < 2; s++) {
        const int kc = s * 4 + lq;
        const int sw = kc ^ l7;
        bf16x8 af[2], bfr[4];
#pragma unroll
        for (int r = 0; r < 2; r++) {
          const int ar = wr * 32 + r * 16 + ln15;
          af[r] = *(const bf16x8*)&sh.g2.As[(ar * 8 + sw) * 8];
        }
#pragma unroll
        for (int c = 0; c < 4; c++) {
          const int br = wc * 64 + c * 16 + ln15;
          bfr[c] = *(const bf16x8*)&sh.g2.Bs[(br * 8 + sw) * 8];
        }
#pragma unroll
        for (int r = 0; r < 2; r++)
#pragma unroll
          for (int c = 0; c < 4; c++)
            acc[r][c] = __builtin_amdgcn_mfma_f32_16x16x32_bf16(af[r], bfr[c], acc[r][c], 0, 0, 0);
      }
      if (kt + 64 < NC) {
        __syncthreads();
        K2_WRITE();
        __syncthreads();
      }
    }
#undef K2_LOAD
#undef K2_WRITE

#pragma unroll
    for (int c = 0; c < 4; c++) {
      const int gcol = n0 + wc * 64 + c * 16 + ln15;
      const int p = gcol >> 10;  // 0=q, 1=k, 2=v
      const int h = (gcol & 1023) >> 6;
      const int hd = gcol & 63;
#pragma unroll
      for (int r = 0; r < 2; r++) {
        const int rbase = m0 + wr * 32 + r * 16 + lq * 4;
#pragma unroll
        for (int g = 0; g < 4; g++) {
          const u16 bq = f2b(quantize(acc[r][c][g]));
          const int row = rbase + g;
          if (p == 0)      qh[(h * T_SEQ + row) * HDIM + hd] = bq;
          else if (p == 1) kh[(h * T_SEQ + row) * HDIM + hd] = bq;
          else             vt[(h * HDIM + hd) * T_SEQ + row] = bq;
        }
      }
    }
  }
  grid.sync();

  // ---------------- P2: attention (1024 tiles grid-strided over 768 blocks) ----------------
  for (int ga = b; ga < 1024; ga += 768) {
    __syncthreads();  // prior iteration's S reads done / union handoff
    const int lin = (ga & 7) * 128 + (ga >> 3);  // XCD head-grouping (bijective)
    const int h = lin >> 6;
    const int i0 = (lin & 63) * 32;
    const int j0 = i0 - 256;

    const u16* qb = qh + (h * T_SEQ + i0) * HDIM;
    const u16* kb = kh + h * T_SEQ * HDIM;

    bf16x8 qf[2][2];
#pragma unroll
    for (int r = 0; r < 2; r++) {
      qf[r][0] = *(const bf16x8*)&qb[(r * 16 + ln15) * HDIM + lq * 8];
      qf[r][1] = *(const bf16x8*)&qb[(r * 16 + ln15) * HDIM + 32 + lq * 8];
    }

    bf16x8 kf[5][2];
#pragma unroll
    for (int t = 0; t < 5; t++) {
      const int jt = j0 + (wave + t * 4) * 16;
      if (jt >= 0 && jt <= T_SEQ - 16) {
        kf[t][0] = *(const bf16x8*)&kb[(jt + ln15) * HDIM + lq * 8];
        kf[t][1] = *(const bf16x8*)&kb[(jt + ln15) * HDIM + 32 + lq * 8];
      } else {
        kf[t][0] = bf16x8{};
        kf[t][1] = bf16x8{};
      }
    }

    // phase 1: swapped QK^T -> mask -> scale -> quantize -> packed b64 S writes
#pragma unroll
    for (int t = 0; t < 5; t++) {
      const int ct = wave + t * 4;
      const int jt = j0 + ct * 16;
#pragma unroll
      for (int rt = 0; rt < 2; rt++) {
        const bool skip = (ct < rt) || (ct > rt + 16) || (jt < 0);
        f32x4 s = {0.f, 0.f, 0.f, 0.f};
        if (!skip) {
          __builtin_amdgcn_s_setprio(1);
          s = __builtin_amdgcn_mfma_f32_16x16x32_bf16(kf[t][0], qf[rt][0], s, 0, 0, 0);
          s = __builtin_amdgcn_mfma_f32_16x16x32_bf16(kf[t][1], qf[rt][1], s, 0, 0, 0);
          __builtin_amdgcn_s_setprio(0);
        }
        const int i = i0 + rt * 16 + ln15;  // col(lane&15)=Q-row, reg=K-col
        ushort4 pk;
        u16* pp = (u16*)&pk;
#pragma unroll
        for (int g2 = 0; g2 < 4; g2++) {
          const int j = jt + lq * 4 + g2;
          float v = -INFINITY;
          if (!skip && j <= i && j > i - WINSZ) v = quantize(s[g2] * 0.125f);
          pp[g2] = f2b(v);
        }
        *(ushort4*)&sh.at.S[(rt * 16 + ln15) * 328 + ct * 16 + lq * 4] = pk;
      }
    }

    // V prefetch: hides under barrier + softmax
    const u16* vb = vt + (h * HDIM + wave * 16 + ln15) * T_SEQ;
    bf16x8 vf[9];
#pragma unroll
    for (int kk = 0; kk < 9; kk++) {
      int jb = j0 + kk * 32 + lq * 8;
      if (jb < 0) jb = 0;
      vf[kk] = *(const bf16x8*)&vb[jb];
    }
    __syncthreads();

    // phase 2: per-row max + unnormalized exp; 8 threads/row
    {
      const int r = tid >> 3, sg = tid & 7;
      u16* Srow = &sh.at.S[r * 328 + sg * 40];
      uint4 ch[5];
      float m = -INFINITY;
#pragma unroll
      for (int c = 0; c < 5; c++) {
        ch[c] = *(const uint4*)&Srow[c * 8];
        const u32* w = (const u32*)&ch[c];
#pragma unroll
        for (int d = 0; d < 4; d++) {
          m = fmaxf(m, b2f((u16)(w[d] & 0xffffu)));
          m = fmaxf(m, b2f((u16)(w[d] >> 16)));
        }
      }
      m = fmaxf(m, __shfl_xor(m, 1));
      m = fmaxf(m, __shfl_xor(m, 2));
      m = fmaxf(m, __shfl_xor(m, 4));
      float l = 0.0f;
#pragma unroll
      for (int c = 0; c < 5; c++) {
        u32* w = (u32*)&ch[c];
#pragma unroll
        for (int d = 0; d < 4; d++) {
          const float e0 = __expf(b2f((u16)(w[d] & 0xffffu)) - m);
          const float e1 = __expf(b2f((u16)(w[d] >> 16)) - m);
          l += e0 + e1;
          w[d] = ((u32)f2b(e1) << 16) | f2b(e0);
        }
        *(uint4*)&Srow[c * 8] = ch[c];
      }
      l += __shfl_xor(l, 1);
      l += __shfl_xor(l, 2);
      l += __shfl_xor(l, 4);
      if (sg == 0) sh.at.Linv[r] = 1.0f / l;
    }
    __syncthreads();

    // phase 3: y = (E @ V^T) * Linv; 9 static kk chunks
    f32x4 acc[2] = {};
#pragma unroll
    for (int kk = 0; kk < 9; kk++) {
#pragma unroll
      for (int rt = 0; rt < 2; rt++) {
        const bf16x8 pf = *(const bf16x8*)&sh.at.S[(rt * 16 + ln15) * 328 + kk * 32 + lq * 8];
        __builtin_amdgcn_s_setprio(1);
        acc[rt] = __builtin_amdgcn_mfma_f32_16x16x32_bf16(pf, vf[kk], acc[rt], 0, 0, 0);
        __builtin_amdgcn_s_setprio(0);
      }
    }
#pragma unroll
    for (int rt = 0; rt < 2; rt++)
#pragma unroll
      for (int g2 = 0; g2 < 4; g2++) {
        const int row = rt * 16 + lq * 4 + g2;
        const int i = i0 + row;
        yq[i * NC + h * HDIM + wave * 16 + ln15] = f2b(quantize(acc[rt][g2] * sh.at.Linv[row]));
      }
  }
  grid.sync();

  // ---------------- P3: proj GEMM (64x64 tile, single-buf, 512 tiles) ----------------
  if (b < 512) {
    const int wr = wave >> 1, wc = wave & 1;
    const int xcd = b & 7, tt = b >> 3;    // XCD rectangle (bijective, 512)
    const int bx = (xcd & 1) * 8 + tt % 8;
    const int by = (xcd >> 1) * 8 + tt / 8;
    const int m0 = by * 64, n0 = bx * 64;

    const int crow = tid >> 3, csl = tid & 7;
    const u16* ag0 = yq + (m0 + crow) * NC + csl * 8;
    const u16* bg0 = wTp + (n0 + crow) * NC + csl * 8;
    const int wofs = crow * 64 + (csl ^ (crow & 7)) * 8;

    uint4 pa0, pa1, pb0, pb1;
    f32x4 acc[2][2] = {};

#define K4_LOAD(KT)                                 \
  {                                                 \
    pa0 = *(const uint4*)(ag0 + (KT));              \
    pa1 = *(const uint4*)(ag0 + 32 * NC + (KT));    \
    pb0 = *(const uint4*)(bg0 + (KT));              \
    pb1 = *(const uint4*)(bg0 + 32 * NC + (KT));    \
  }
#define K4_WRITE()                                  \
  {                                                 \
    *(uint4*)&sh.g4.As[wofs] = pa0;                 \
    *(uint4*)&sh.g4.As[wofs + 2048] = pa1;          \
    *(uint4*)&sh.g4.Bs[wofs] = pb0;                 \
    *(uint4*)&sh.g4.Bs[wofs + 2048] = pb1;          \
  }

    __syncthreads();  // P2 LDS reads complete before union reuse
    K4_LOAD(0);
    K4_WRITE();
    __syncthreads();

    for (int kt = 0; kt < NC; kt += 64) {
      if (kt + 64 < NC) K4_LOAD(kt + 64);
#pragma unroll
      for (int s = 0; s < 2; s++) {
        const int kc = s * 4 + lq;
        const int sw = kc ^ l7;
        bf16x8 af[2], bfr[2];
#pragma unroll
        for (int r = 0; r < 2; r++) {
          const int ar = wr * 32 + r * 16 + ln15;
          af[r] = *(const bf16x8*)&sh.g4.As[(ar * 8 + sw) * 8];
        }
#pragma unroll
        for (int c = 0; c < 2; c++) {
          const int br = wc * 32 + c * 16 + ln15;
          bfr[c] = *(const bf16x8*)&sh.g4.Bs[(br * 8 + sw) * 8];
        }
#pragma unroll
        for (int r = 0; r < 2; r++)
#pragma unroll
          for (int c = 0; c < 2; c++)
            acc[r][c] = __builtin_amdgcn_mfma_f32_16x16x32_bf16(af[r], bfr[c], acc[r][c], 0, 0, 0);
      }
      if (kt + 64 < NC) {
        __syncthreads();
        K4_WRITE();
        __syncthreads();
      }
    }
#undef K4_LOAD
#undef K4_WRITE

#pragma unroll
    for (int r = 0; r < 2; r++)
#pragma unroll
      for (int g = 0; g < 4; g++) {
        const int row = m0 + wr * 32 + r * 16 + lq * 4 + g;
#pragma unroll
        for (int c = 0; c < 2; c++)
          out[(long)row * NC + n0 + wc * 32 + c * 16 + ln15] = acc[r][c][g];
      }
  }
}

// ================= fallback path: the verified R12 four-kernel pipeline =================
__global__ __launch_bounds__(256) void k1_prep(const float* __restrict__ x, u16* __restrict__ xb,
                                               const float* __restrict__ wa, u16* __restrict__ wTa,
                                               const float* __restrict__ wp, u16* __restrict__ wTp) {
  if (blockIdx.z == 2) {
    const int nb = gridDim.x * gridDim.y;
    const int bid = blockIdx.y * gridDim.x + blockIdx.x;
    const int n4 = T_SEQ * NC / 4;
    for (int i = bid * 256 + threadIdx.x; i < n4; i += nb * 256) {
      const float4 v = ((const float4*)x)[i];
      ushort4 o;
      o.x = f2b(v.x); o.y = f2b(v.y); o.z = f2b(v.z); o.w = f2b(v.w);
      ((ushort4*)xb)[i] = o;
    }
    return;
  }
  const int iswp = (blockIdx.z == 1);
  if (iswp && blockIdx.x >= 16) return;
  const float* in = iswp ? wp : wa;
  u16* out = iswp ? wTp : wTa;
  const int Cc = iswp ? 1024 : 3072;
  __shared__ u16 tile[64][65];
  const int tc = blockIdx.x * 64, tr = blockIdx.y * 64;
  const int lx = threadIdx.x & 63, ly = threadIdx.x >> 6;
#pragma unroll
  for (int r = ly; r < 64; r += 4)
    tile[r][lx] = f2b(in[(long)(tr + r) * Cc + tc + lx]);
  __syncthreads();
  const int e = threadIdx.x & 31;
  const int r0 = (threadIdx.x >> 5) & 1;
  const int w = threadIdx.x >> 6;
#pragma unroll
  for (int it = 0; it < 8; it++) {
    const int r = it * 8 + w * 2 + r0;
    ushort2 o2;
    o2.x = tile[2 * e][r];
    o2.y = tile[2 * e + 1][r];
    *(ushort2*)&out[(tc + r) * 1024 + tr + 2 * e] = o2;
  }
}

__global__ __launch_bounds__(256, 3) void k2_qkv(const u16* __restrict__ A,
                                                 const u16* __restrict__ BT,
                                                 u16* __restrict__ o0, u16* __restrict__ o1,
                                                 u16* __restrict__ o2) {
  __shared__ __align__(16) u16 As[2][4096];
  __shared__ __align__(16) u16 Bs[2][8192];
  const int tid = threadIdx.x;
  const int lane = tid & 63;
  const int wave = tid >> 6;
  const int wr = wave >> 1, wc = wave & 1;
  const int ln15 = lane & 15, lq = lane >> 4;
  const int l7 = ln15 & 7;

  const int wg = blockIdx.y * 24 + blockIdx.x;
  const int xcd = wg & 7, t = wg >> 3;
  const int bx = (xcd & 1) * 12 + t % 12;
  const int by = (xcd >> 1) * 8 + t / 12;
  const int m0 = by * 64, n0 = bx * 128;

  const int crow = tid >> 3, csl = tid & 7;
  const u16* ag0 = A + (m0 + crow) * NC + csl * 8;
  const u16* bg0 = BT + (n0 + crow) * NC + csl * 8;
  const int wofs = crow * 64 + (csl ^ (crow & 7)) * 8;

  uint4 pa0, pa1, pb0, pb1, pb2, pb3;
  uint4 qa0, qa1, qb0, qb1, qb2, qb3;
  f32x4 acc[2][4] = {};

#define K2_LOADP(KT)                                  \
  {                                                   \
    pa0 = *(const uint4*)(ag0 + (KT));                \
    pa1 = *(const uint4*)(ag0 + 32 * NC + (KT));      \
    pb0 = *(const uint4*)(bg0 + (KT));                \
    pb1 = *(const uint4*)(bg0 + 32 * NC + (KT));      \
    pb2 = *(const uint4*)(bg0 + 64 * NC + (KT));      \
    pb3 = *(const uint4*)(bg0 + 96 * NC + (KT));      \
  }
#define K2_LOADQ(KT)                                  \
  {                                                   \
    qa0 = *(const uint4*)(ag0 + (KT));                \
    qa1 = *(const uint4*)(ag0 + 32 * NC + (KT));      \
    qb0 = *(const uint4*)(bg0 + (KT));                \
    qb1 = *(const uint4*)(bg0 + 32 * NC + (KT));      \
    qb2 = *(const uint4*)(bg0 + 64 * NC + (KT));      \
    qb3 = *(const uint4*)(bg0 + 96 * NC + (KT));      \
  }
#define K2_WRITEP(BUF)                                \
  {                                                   \
    *(uint4*)&As[BUF][wofs] = pa0;                    \
    *(uint4*)&As[BUF][wofs + 2048] = pa1;             \
    *(uint4*)&Bs[BUF][wofs] = pb0;                    \
    *(uint4*)&Bs[BUF][wofs + 2048] = pb1;             \
    *(uint4*)&Bs[BUF][wofs + 4096] = pb2;             \
    *(uint4*)&Bs[BUF][wofs + 6144] = pb3;             \
  }
#define K2_WRITEQ(BUF)                                \
  {                                                   \
    *(uint4*)&As[BUF][wofs] = qa0;                    \
    *(uint4*)&As[BUF][wofs + 2048] = qa1;             \
    *(uint4*)&Bs[BUF][wofs] = qb0;                    \
    *(uint4*)&Bs[BUF][wofs + 2048] = qb1;             \
    *(uint4*)&Bs[BUF][wofs + 4096] = qb2;             \
    *(uint4*)&Bs[BUF][wofs + 6144] = qb3;             \
  }

  auto compute = [&](const u16* LA, const u16* LB) {
#pragma unroll
    for (int s = 0; s < 2; s++) {
      const int kc = s * 4 + lq;
      const int sw = kc ^ l7;
      bf16x8 af[2], bfr[4];
#pragma unroll
      for (int r = 0; r < 2; r++) {
        const int ar = wr * 32 + r * 16 + ln15;
        af[r] = *(const bf16x8*)&LA[(ar * 8 + sw) * 8];
      }
#pragma unroll
      for (int c = 0; c < 4; c++) {
        const int br = wc * 64 + c * 16 + ln15;
        bfr[c] = *(const bf16x8*)&LB[(br * 8 + sw) * 8];
      }
#pragma unroll
      for (int r = 0; r < 2; r++)
#pragma unroll
        for (int c = 0; c < 4; c++)
          acc[r][c] = __builtin_amdgcn_mfma_f32_16x16x32_bf16(af[r], bfr[c], acc[r][c], 0, 0, 0);
    }
  };

  K2_LOADP(0);
  K2_WRITEP(0);
  K2_LOADQ(64);

  for (int kt = 0; kt < NC; kt += 128) {
    __syncthreads();
    if (kt + 128 < NC) K2_LOADP(kt + 128);
    compute(As[0], Bs[0]);
    K2_WRITEQ(1);
    __syncthreads();
    if (kt + 192 < NC) K2_LOADQ(kt + 192);
    compute(As[1], Bs[1]);
    if (kt + 128 < NC) K2_WRITEP(0);
  }
#undef K2_LOADP
#undef K2_LOADQ
#undef K2_WRITEP
#undef K2_WRITEQ

#pragma unroll
  for (int c = 0; c < 4; c++) {
    const int gcol = n0 + wc * 64 + c * 16 + ln15;
    const int p = gcol >> 10;
    const int h = (gcol & 1023) >> 6;
    const int hd = gcol & 63;
#pragma unroll
    for (int r = 0; r < 2; r++) {
      const int rbase = m0 + wr * 32 + r * 16 + lq * 4;
#pragma unroll
      for (int g = 0; g < 4; g++) {
        const u16 b = f2b(quantize(acc[r][c][g]));
        const int row = rbase + g;
        if (p == 0)      o0[(h * T_SEQ + row) * HDIM + hd] = b;
        else if (p == 1) o1[(h * T_SEQ + row) * HDIM + hd] = b;
        else             o2[(h * HDIM + hd) * T_SEQ + row] = b;
      }
    }
  }
}

__global__ __launch_bounds__(256, 4) void k3_attn(const u16* __restrict__ qh,
                                                  const u16* __restrict__ kh,
                                                  const u16* __restrict__ vt,
                                                  u16* __restrict__ yq) {
  __shared__ __align__(16) u16 S[32 * 328];
  __shared__ float Linv[32];
  const int tid = threadIdx.x;
  const int lane = tid & 63;
  const int wave = tid >> 6;
  const int ln15 = lane & 15, lq = lane >> 4;

  const int g = blockIdx.y * 64 + blockIdx.x;
  const int lin = (g & 7) * 128 + (g >> 3);
  const int h = lin >> 6;
  const int i0 = (lin & 63) * 32;
  const int j0 = i0 - 256;

  const u16* qb = qh + (h * T_SEQ + i0) * HDIM;
  const u16* kb = kh + h * T_SEQ * HDIM;

  bf16x8 qf[2][2];
#pragma unroll
  for (int r = 0; r < 2; r++) {
    qf[r][0] = *(const bf16x8*)&qb[(r * 16 + ln15) * HDIM + lq * 8];
    qf[r][1] = *(const bf16x8*)&qb[(r * 16 + ln15) * HDIM + 32 + lq * 8];
  }

  bf16x8 kf[5][2];
#pragma unroll
  for (int t = 0; t < 5; t++) {
    const int jt = j0 + (wave + t * 4) * 16;
    if (jt >= 0 && jt <= T_SEQ - 16) {
      kf[t][0] = *(const bf16x8*)&kb[(jt + ln15) * HDIM + lq * 8];
      kf[t][1] = *(const bf16x8*)&kb[(jt + ln15) * HDIM + 32 + lq * 8];
    } else {
      kf[t][0] = bf16x8{};
      kf[t][1] = bf16x8{};
    }
  }

#pragma unroll
  for (int t = 0; t < 5; t++) {
    const int ct = wave + t * 4;
    const int jt = j0 + ct * 16;
#pragma unroll
    for (int rt = 0; rt < 2; rt++) {
      const bool skip = (ct < rt) || (ct > rt + 16) || (jt < 0);
      f32x4 s = {0.f, 0.f, 0.f, 0.f};
      if (!skip) {
        __builtin_amdgcn_s_setprio(1);
        s = __builtin_amdgcn_mfma_f32_16x16x32_bf16(kf[t][0], qf[rt][0], s, 0, 0, 0);
        s = __builtin_amdgcn_mfma_f32_16x16x32_bf16(kf[t][1], qf[rt][1], s, 0, 0, 0);
        __builtin_amdgcn_s_setprio(0);
      }
      const int i = i0 + rt * 16 + ln15;
      ushort4 pk;
      u16* pp = (u16*)&pk;
#pragma unroll
      for (int g2 = 0; g2 < 4; g2++) {
        const int j = jt + lq * 4 + g2;
        float v = -INFINITY;
        if (!skip && j <= i && j > i - WINSZ) v = quantize(s[g2] * 0.125f);
        pp[g2] = f2b(v);
      }
      *(ushort4*)&S[(rt * 16 + ln15) * 328 + ct * 16 + lq * 4] = pk;
    }
  }

  const u16* vb = vt + (h * HDIM + wave * 16 + ln15) * T_SEQ;
  bf16x8 vf[9];
#pragma unroll
  for (int kk = 0; kk < 9; kk++) {
    int jb = j0 + kk * 32 + lq * 8;
    if (jb < 0) jb = 0;
    vf[kk] = *(const bf16x8*)&vb[jb];
  }
  __syncthreads();

  {
    const int r = tid >> 3, sg = tid & 7;
    u16* Srow = &S[r * 328 + sg * 40];
    uint4 ch[5];
    float m = -INFINITY;
#pragma unroll
    for (int c = 0; c < 5; c++) {
      ch[c] = *(const uint4*)&Srow[c * 8];
      const u32* w = (const u32*)&ch[c];
#pragma unroll
      for (int d = 0; d < 4; d++) {
        m = fmaxf(m, b2f((u16)(w[d] & 0xffffu)));
        m = fmaxf(m, b2f((u16)(w[d] >> 16)));
      }
    }
    m = fmaxf(m, __shfl_xor(m, 1));
    m = fmaxf(m, __shfl_xor(m, 2));
    m = fmaxf(m, __shfl_xor(m, 4));
    float l = 0.0f;
#pragma unroll
    for (int c = 0; c < 5; c++) {
      u32* w = (u32*)&ch[c];
#pragma unroll
      for (int d = 0; d < 4; d++) {
        const float e0 = __expf(b2f((u16)(w[d] & 0xffffu)) - m);
        const float e1 = __expf(b2f((u16)(w[d] >> 16)) - m);
        l += e0 + e1;
        w[d] = ((u32)f2b(e1) << 16) | f2b(e0);
      }
      *(uint4*)&Srow[c * 8] = ch[c];
    }
    l += __shfl_xor(l, 1);
    l += __shfl_xor(l, 2);
    l += __shfl_xor(l, 4);
    if (sg == 0) Linv[r] = 1.0f / l;
  }
  __syncthreads();

  f32x4 acc[2] = {};
#pragma unroll
  for (int kk = 0; kk < 9; kk++) {
#pragma unroll
    for (int rt = 0; rt < 2; rt++) {
      const bf16x8 pf = *(const bf16x8*)&S[(rt * 16 + ln15) * 328 + kk * 32 + lq * 8];
      __builtin_amdgcn_s_setprio(1);
      acc[rt] = __builtin_amdgcn_mfma_f32_16x16x32_bf16(pf, vf[kk], acc[rt], 0, 0, 0);
      __builtin_amdgcn_s_setprio(0);
    }
  }
#pragma unroll
  for (int rt = 0; rt < 2; rt++)
#pragma unroll
    for (int g2 = 0; g2 < 4; g2++) {
      const int row = rt * 16 + lq * 4 + g2;
      const int i = i0 + row;
      yq[i * NC + h * HDIM + wave * 16 + ln15] = f2b(quantize(acc[rt][g2] * Linv[row]));
    }
}

__global__ __launch_bounds__(256, 4) void k4_proj(const u16* __restrict__ A,
                                                  const u16* __restrict__ BT,
                                                  float* __restrict__ of) {
  __shared__ __align__(16) u16 As[2][4096];
  __shared__ __align__(16) u16 Bs[2][4096];
  const int tid = threadIdx.x;
  const int lane = tid & 63;
  const int wave = tid >> 6;
  const int wr = wave >> 1, wc = wave & 1;
  const int ln15 = lane & 15, lq = lane >> 4;
  const int l7 = ln15 & 7;

  const int wg = blockIdx.y * 16 + blockIdx.x;
  const int xcd = wg & 7, t = wg >> 3;
  const int bx = (xcd & 1) * 8 + t % 8;
  const int by = (xcd >> 1) * 8 + t / 8;
  const int m0 = by * 64, n0 = bx * 64;

  const int crow = tid >> 3, csl = tid & 7;
  const u16* ag0 = A + (m0 + crow) * NC + csl * 8;
  const u16* bg0 = BT + (n0 + crow) * NC + csl * 8;
  const int wofs = crow * 64 + (csl ^ (crow & 7)) * 8;

  uint4 pa0, pa1, pb0, pb1;
  uint4 qa0, qa1, qb0, qb1;
  f32x4 acc[2][2] = {};

#define K4_LOADP(KT)                               \
  {                                                \
    pa0 = *(const uint4*)(ag0 + (KT));             \
    pa1 = *(const uint4*)(ag0 + 32 * NC + (KT));   \
    pb0 = *(const uint4*)(bg0 + (KT));             \
    pb1 = *(const uint4*)(bg0 + 32 * NC + (KT));   \
  }
#define K4_LOADQ(KT)                               \
  {                                                \
    qa0 = *(const uint4*)(ag0 + (KT));             \
    qa1 = *(const uint4*)(ag0 + 32 * NC + (KT));   \
    qb0 = *(const uint4*)(bg0 + (KT));             \
    qb1 = *(const uint4*)(bg0 + 32 * NC + (KT));   \
  }
#define K4_WRITEP(BUF)                             \
  {                                                \
    *(uint4*)&As[BUF][wofs] = pa0;                 \
    *(uint4*)&As[BUF][wofs + 2048] = pa1;          \
    *(uint4*)&Bs[BUF][wofs] = pb0;                 \
    *(uint4*)&Bs[BUF][wofs + 2048] = pb1;          \
  }
#define K4_WRITEQ(BUF)                             \
  {                                                \
    *(uint4*)&As[BUF][wofs] = qa0;                 \
    *(uint4*)&As[BUF][wofs + 2048] = qa1;          \
    *(uint4*)&Bs[BUF][wofs] = qb0;                 \
    *(uint4*)&Bs[BUF][wofs + 2048] = qb1;          \
  }

  auto compute = [&](const u16* LA, const u16* LB) {
#pragma unroll
    for (int s = 0; s < 2; s++) {
      const int kc = s * 4 + lq;
      const int sw = kc ^ l7;
      bf16x8 af[2], bfr[2];
#pragma unroll
      for (int r = 0; r < 2; r++) {
        const int ar = wr * 32 + r * 16 + ln15;
        af[r] = *(const bf16x8*)&LA[(ar * 8 + sw) * 8];
      }
#pragma unroll
      for (int c = 0; c < 2; c++) {
        const int br = wc * 32 + c * 16 + ln15;
        bfr[c] = *(const bf16x8*)&LB[(br * 8 + sw) * 8];
      }
#pragma unroll
      for (int r = 0; r < 2; r++)
#pragma unroll
        for (int c = 0; c < 2; c++)
          acc[r][c] = __builtin_amdgcn_mfma_f32_16x16x32_bf16(af[r], bfr[c], acc[r][c], 0, 0, 0);
    }
  };

  K4_LOADP(0);
  K4_WRITEP(0);
  K4_LOADQ(64);

  for (int kt = 0; kt < NC; kt += 128) {
    __syncthreads();
    if (kt + 128 < NC) K4_LOADP(kt + 128);
    compute(As[0], Bs[0]);
    K4_WRITEQ(1);
    __syncthreads();
    if (kt + 192 < NC) K4_LOADQ(kt + 192);
    compute(As[1], Bs[1]);
    if (kt + 128 < NC) K4_WRITEP(0);
  }
#undef K4_LOADP
#undef K4_LOADQ
#undef K4_WRITEP
#undef K4_WRITEQ

#pragma unroll
  for (int r = 0; r < 2; r++)
#pragma unroll
    for (int g = 0; g < 4; g++) {
      const int row = m0 + wr * 32 + r * 16 + lq * 4 + g;
#pragma unroll
      for (int c = 0; c < 2; c++)
        of[(long)row * NC + n0 + wc * 32 + c * 16 + ln15] = acc[r][c][g];
    }
}

// ---- launch ----
extern "C" void kernel_launch(void* const* d_in, const int* in_sizes, int n_in,
                              void* d_out, int out_size, void* d_ws, size_t ws_size,
                              hipStream_t stream) {
  const void *px = d_in[0], *pwa = d_in[1], *pwp = d_in[2];
  for (int i = 0; i < n_in; i++) {
    if (in_sizes[i] == 2048 * 1024) px = d_in[i];
    else if (in_sizes[i] == 3072 * 1024) pwa = d_in[i];
    else if (in_sizes[i] == 1024 * 1024) pwp = d_in[i];
  }

  char* ws = (char*)d_ws;
  u16* xb  = (u16*)(ws + (1u << 20));    // [2048][1024]  4 MB
  u16* wTa = (u16*)(ws + (5u << 20));    // [3072][1024]  6 MB
  u16* wTp = (u16*)(ws + (11u << 20));   // [1024][1024]  2 MB
  u16* qh  = (u16*)(ws + (13u << 20));   // [16][2048][64] 4 MB
  u16* kh  = (u16*)(ws + (17u << 20));   // 4 MB
  u16* vt  = (u16*)(ws + (21u << 20));   // [16][64][2048] 4 MB
  u16* yq  = (u16*)(ws + (25u << 20));   // [2048][1024]  4 MB

  const float* a0 = (const float*)px;
  u16* a1 = xb;
  const float* a2 = (const float*)pwa;
  u16* a3 = wTa;
  const float* a4 = (const float*)pwp;
  u16* a5 = wTp;
  u16* a6 = qh;
  u16* a7 = kh;
  u16* a8 = vt;
  u16* a9 = yq;
  float* a10 = (float*)d_out;
  void* args[] = {&a0, &a1, &a2, &a3, &a4, &a5, &a6, &a7, &a8, &a9, &a10};

  hipError_t rc = hipLaunchCooperativeKernel(reinterpret_cast<const void*>(&fused), dim3(768),
                                             dim3(256), args, 0, stream);
  if (rc != hipSuccess) {
    (void)hipGetLastError();  // clear sticky error; fall back to verified 4-kernel path
    k1_prep<<<dim3(48, 16, 3), 256, 0, stream>>>((const float*)px, xb, (const float*)pwa, wTa,
                                                 (const float*)pwp, wTp);
    k2_qkv<<<dim3(24, 32), 256, 0, stream>>>(xb, wTa, qh, kh, vt);
    k3_attn<<<dim3(64, 16), 256, 0, stream>>>(qh, kh, vt, yq);
    k4_proj<<<dim3(16, 32), 256, 0, stream>>>(yq, wTp, (float*)d_out);
  }
}

// Round 15
// 123.882 us; speedup vs baseline: 3.3076x; 3.3076x over previous
//
#include <hip/hip_runtime.h>

using u16 = unsigned short;
using u32 = unsigned int;

typedef __bf16 bf16x8 __attribute__((ext_vector_type(8)));
typedef float f32x4 __attribute__((ext_vector_type(4)));

#define T_SEQ 2048
#define NC 1024
#define HDIM 64
#define WINSZ 256
#define QSTEP (2.0f / 255.0f)

__device__ __forceinline__ float b2f(u16 u) {
  u32 v = ((u32)u) << 16;
  return __builtin_bit_cast(float, v);
}
__device__ __forceinline__ u16 f2b(float f) {
  u32 x = __builtin_bit_cast(u32, f);
  u32 r = (x + 0x7fffu + ((x >> 16) & 1u)) >> 16;  // RNE
  return (u16)r;
}
__device__ __forceinline__ float quantize(float v) {
  v = fminf(fmaxf(v, -1.0f), 1.0f);
  return QSTEP * rintf(v / QSTEP);
}

// ---- prep: z=0 transpose w_attn, z=1 transpose w_proj, z=2 convert x (all fp32 -> bf16) ----
__global__ __launch_bounds__(256) void k1_prep(const float* __restrict__ x, u16* __restrict__ xb,
                                               const float* __restrict__ wa, u16* __restrict__ wTa,
                                               const float* __restrict__ wp, u16* __restrict__ wTp) {
  if (blockIdx.z == 2) {  // x convert, vectorized x4, grid-stride
    const int nb = gridDim.x * gridDim.y;
    const int bid = blockIdx.y * gridDim.x + blockIdx.x;
    const int n4 = T_SEQ * NC / 4;
    for (int i = bid * 256 + threadIdx.x; i < n4; i += nb * 256) {
      const float4 v = ((const float4*)x)[i];
      ushort4 o;
      o.x = f2b(v.x); o.y = f2b(v.y); o.z = f2b(v.z); o.w = f2b(v.w);
      ((ushort4*)xb)[i] = o;
    }
    return;
  }
  const int iswp = (blockIdx.z == 1);
  if (iswp && blockIdx.x >= 16) return;
  const float* in = iswp ? wp : wa;
  u16* out = iswp ? wTp : wTa;
  const int Cc = iswp ? 1024 : 3072;
  __shared__ u16 tile[64][65];
  const int tc = blockIdx.x * 64, tr = blockIdx.y * 64;
  const int lx = threadIdx.x & 63, ly = threadIdx.x >> 6;
#pragma unroll
  for (int r = ly; r < 64; r += 4)
    tile[r][lx] = f2b(in[(long)(tr + r) * Cc + tc + lx]);
  __syncthreads();
  // write: lane -> ushort2 (2 consecutive out cols); wave covers 2 out rows per instr.
  const int e = threadIdx.x & 31;
  const int r0 = (threadIdx.x >> 5) & 1;
  const int w = threadIdx.x >> 6;
#pragma unroll
  for (int it = 0; it < 8; it++) {
    const int r = it * 8 + w * 2 + r0;  // out row within tile [0,64)
    ushort2 o2;
    o2.x = tile[2 * e][r];
    o2.y = tile[2 * e + 1][r];
    *(ushort2*)&out[(tc + r) * 1024 + tr + 2 * e] = o2;
  }
}

// ---- qkv GEMM: 64x128 tile, BK=64, DEPTH-3 register pipeline + LDS dbuf ----
// Coalesced chunk map (R6, -2x) + XOR bank-swizzle; loads two tiles ahead in named
// scalar reg sets (no arrays -> no scratch, R5 lesson).
__global__ __launch_bounds__(256, 3) void k2_qkv(const u16* __restrict__ A,
                                                 const u16* __restrict__ BT,
                                                 u16* __restrict__ o0, u16* __restrict__ o1,
                                                 u16* __restrict__ o2) {
  __shared__ __align__(16) u16 As[2][4096];  // [buf][row:64][slot:8][8]   8KB each
  __shared__ __align__(16) u16 Bs[2][8192];  // [buf][row:128][slot:8][8] 16KB each
  const int tid = threadIdx.x;
  const int lane = tid & 63;
  const int wave = tid >> 6;
  const int wr = wave >> 1, wc = wave & 1;  // wave: rows wr*32+[0,32), cols wc*64+[0,64)
  const int ln15 = lane & 15, lq = lane >> 4;
  const int l7 = ln15 & 7;

  // XCD rectangle partition (bijective: 8 xcd x 12 bx x 8 by = 768 = 24x32)
  const int wg = blockIdx.y * 24 + blockIdx.x;
  const int xcd = wg & 7, t = wg >> 3;     // t in [0,96)
  const int bx = (xcd & 1) * 12 + t % 12;  // [0,24)
  const int by = (xcd >> 1) * 8 + t / 12;  // [0,32)
  const int m0 = by * 64, n0 = bx * 128;

  // staging addresses: chunk (crow, csl); this thread covers rows crow+32k
  const int crow = tid >> 3, csl = tid & 7;
  const u16* ag0 = A + (m0 + crow) * NC + csl * 8;   // + 32*NC for second A chunk
  const u16* bg0 = BT + (n0 + crow) * NC + csl * 8;  // + {32,64,96}*NC for B chunks
  const int wofs = crow * 64 + (csl ^ (crow & 7)) * 8;  // u16 elements; +2048 per 32 rows

  // two staging sets (named scalars -> VGPRs, never scratch)
  uint4 pa0, pa1, pb0, pb1, pb2, pb3;  // set P
  uint4 qa0, qa1, qb0, qb1, qb2, qb3;  // set Q
  f32x4 acc[2][4] = {};

#define K2_LOADP(KT)                                  \
  {                                                   \
    pa0 = *(const uint4*)(ag0 + (KT));                \
    pa1 = *(const uint4*)(ag0 + 32 * NC + (KT));      \
    pb0 = *(const uint4*)(bg0 + (KT));                \
    pb1 = *(const uint4*)(bg0 + 32 * NC + (KT));      \
    pb2 = *(const uint4*)(bg0 + 64 * NC + (KT));      \
    pb3 = *(const uint4*)(bg0 + 96 * NC + (KT));      \
  }
#define K2_LOADQ(KT)                                  \
  {                                                   \
    qa0 = *(const uint4*)(ag0 + (KT));                \
    qa1 = *(const uint4*)(ag0 + 32 * NC + (KT));      \
    qb0 = *(const uint4*)(bg0 + (KT));                \
    qb1 = *(const uint4*)(bg0 + 32 * NC + (KT));      \
    qb2 = *(const uint4*)(bg0 + 64 * NC + (KT));      \
    qb3 = *(const uint4*)(bg0 + 96 * NC + (KT));      \
  }
#define K2_WRITEP(BUF)                                \
  {                                                   \
    *(uint4*)&As[BUF][wofs] = pa0;                    \
    *(uint4*)&As[BUF][wofs + 2048] = pa1;             \
    *(uint4*)&Bs[BUF][wofs] = pb0;                    \
    *(uint4*)&Bs[BUF][wofs + 2048] = pb1;             \
    *(uint4*)&Bs[BUF][wofs + 4096] = pb2;             \
    *(uint4*)&Bs[BUF][wofs + 6144] = pb3;             \
  }
#define K2_WRITEQ(BUF)                                \
  {                                                   \
    *(uint4*)&As[BUF][wofs] = qa0;                    \
    *(uint4*)&As[BUF][wofs + 2048] = qa1;             \
    *(uint4*)&Bs[BUF][wofs] = qb0;                    \
    *(uint4*)&Bs[BUF][wofs + 2048] = qb1;             \
    *(uint4*)&Bs[BUF][wofs + 4096] = qb2;             \
    *(uint4*)&Bs[BUF][wofs + 6144] = qb3;             \
  }

  auto compute = [&](const u16* LA, const u16* LB) {
#pragma unroll
    for (int s = 0; s < 2; s++) {
      const int kc = s * 4 + lq;
      const int sw = kc ^ l7;  // swizzled slot (row&7 == l7 for all fragment rows)
      bf16x8 af[2], bfr[4];
#pragma unroll
      for (int r = 0; r < 2; r++) {
        const int ar = wr * 32 + r * 16 + ln15;
        af[r] = *(const bf16x8*)&LA[(ar * 8 + sw) * 8];
      }
#pragma unroll
      for (int c = 0; c < 4; c++) {
        const int br = wc * 64 + c * 16 + ln15;
        bfr[c] = *(const bf16x8*)&LB[(br * 8 + sw) * 8];
      }
#pragma unroll
      for (int r = 0; r < 2; r++)
#pragma unroll
        for (int c = 0; c < 4; c++)
          acc[r][c] = __builtin_amdgcn_mfma_f32_16x16x32_bf16(af[r], bfr[c], acc[r][c], 0, 0, 0);
    }
  };

  // prologue: tile0 -> P -> buf0; tile1 -> Q (writes after first compute)
  K2_LOADP(0);
  K2_WRITEP(0);
  K2_LOADQ(64);

  for (int kt = 0; kt < NC; kt += 128) {
    __syncthreads();                          // buf0 (tile kt) visible
    if (kt + 128 < NC) K2_LOADP(kt + 128);    // tile kt+2 -> P
    compute(As[0], Bs[0]);                    // tile kt
    K2_WRITEQ(1);                             // tile kt+1 -> buf1
    __syncthreads();                          // buf1 visible
    if (kt + 192 < NC) K2_LOADQ(kt + 192);    // tile kt+3 -> Q
    compute(As[1], Bs[1]);                    // tile kt+1
    if (kt + 128 < NC) K2_WRITEP(0);          // tile kt+2 -> buf0
  }
#undef K2_LOADP
#undef K2_LOADQ
#undef K2_WRITEP
#undef K2_WRITEQ

#pragma unroll
  for (int c = 0; c < 4; c++) {
    const int gcol = n0 + wc * 64 + c * 16 + ln15;
    const int p = gcol >> 10;  // 0=q, 1=k, 2=v
    const int h = (gcol & 1023) >> 6;
    const int hd = gcol & 63;
#pragma unroll
    for (int r = 0; r < 2; r++) {
      const int rbase = m0 + wr * 32 + r * 16 + lq * 4;
#pragma unroll
      for (int g = 0; g < 4; g++) {
        const u16 b = f2b(quantize(acc[r][c][g]));
        const int row = rbase + g;
        if (p == 0)      o0[(h * T_SEQ + row) * HDIM + hd] = b;
        else if (p == 1) o1[(h * T_SEQ + row) * HDIM + hd] = b;
        else             o2[(h * HDIM + hd) * T_SEQ + row] = b;
      }
    }
  }
}

// ---- attention: one block per (32 queries, head); grid (64,16)=1024 blocks = 4/CU.
// V-loads before first barrier; swapped-operand QK^T with packed b64 S writes. ----
__global__ __launch_bounds__(256, 4) void k3_attn(const u16* __restrict__ qh,
                                                  const u16* __restrict__ kh,
                                                  const u16* __restrict__ vt,
                                                  u16* __restrict__ yq) {
  __shared__ __align__(16) u16 S[32 * 328];  // row stride 328 u16 = 656 B; 20.5 KB
  __shared__ float Linv[32];
  const int tid = threadIdx.x;
  const int lane = tid & 63;
  const int wave = tid >> 6;
  const int ln15 = lane & 15, lq = lane >> 4;

  // XCD swizzle: g -> lin = (g&7)*128 + g>>3 ; h = lin>>6 (2 heads/XCD), qblk = lin&63
  const int g = blockIdx.y * 64 + blockIdx.x;
  const int lin = (g & 7) * 128 + (g >> 3);
  const int h = lin >> 6;
  const int i0 = (lin & 63) * 32;
  const int j0 = i0 - 256;  // key col c in [0,320) -> j = j0 + c

  const u16* qb = qh + (h * T_SEQ + i0) * HDIM;
  const u16* kb = kh + h * T_SEQ * HDIM;

  bf16x8 qf[2][2];
#pragma unroll
  for (int r = 0; r < 2; r++) {
    qf[r][0] = *(const bf16x8*)&qb[(r * 16 + ln15) * HDIM + lq * 8];
    qf[r][1] = *(const bf16x8*)&qb[(r * 16 + ln15) * HDIM + 32 + lq * 8];
  }

  // prefetch K fragments for this wave's 5 column-tiles (ct = wave + 4t covers [0,20))
  bf16x8 kf[5][2];
#pragma unroll
  for (int t = 0; t < 5; t++) {
    const int jt = j0 + (wave + t * 4) * 16;
    if (jt >= 0 && jt <= T_SEQ - 16) {
      kf[t][0] = *(const bf16x8*)&kb[(jt + ln15) * HDIM + lq * 8];
      kf[t][1] = *(const bf16x8*)&kb[(jt + ln15) * HDIM + 32 + lq * 8];
    } else {
      kf[t][0] = bf16x8{};
      kf[t][1] = bf16x8{};
    }
  }

  // phase 1: swapped QK^T -> mask -> scale -> quantize -> packed b64 S writes
#pragma unroll
  for (int t = 0; t < 5; t++) {
    const int ct = wave + t * 4;
    const int jt = j0 + ct * 16;
#pragma unroll
    for (int rt = 0; rt < 2; rt++) {
      const bool skip = (ct < rt) || (ct > rt + 16) || (jt < 0);
      f32x4 s = {0.f, 0.f, 0.f, 0.f};
      if (!skip) {
        __builtin_amdgcn_s_setprio(1);
        s = __builtin_amdgcn_mfma_f32_16x16x32_bf16(kf[t][0], qf[rt][0], s, 0, 0, 0);
        s = __builtin_amdgcn_mfma_f32_16x16x32_bf16(kf[t][1], qf[rt][1], s, 0, 0, 0);
        __builtin_amdgcn_s_setprio(0);
      }
      // D layout: col(lane&15) = Q-row index, row(lq*4+g2) = K-col index
      const int i = i0 + rt * 16 + ln15;
      ushort4 pk;
      u16* pp = (u16*)&pk;
#pragma unroll
      for (int g2 = 0; g2 < 4; g2++) {
        const int j = jt + lq * 4 + g2;
        float v = -INFINITY;
        if (!skip && j <= i && j > i - WINSZ) v = quantize(s[g2] * 0.125f);
        pp[g2] = f2b(v);
      }
      *(ushort4*)&S[(rt * 16 + ln15) * 328 + ct * 16 + lq * 4] = pk;
    }
  }

  // V prefetch (independent of S): latency hides under barrier + phase-2 softmax.
  const u16* vb = vt + (h * HDIM + wave * 16 + ln15) * T_SEQ;
  bf16x8 vf[9];
#pragma unroll
  for (int kk = 0; kk < 9; kk++) {
    int jb = j0 + kk * 32 + lq * 8;
    if (jb < 0) jb = 0;  // unused when masked; keep load in-bounds
    vf[kk] = *(const bf16x8*)&vb[jb];
  }
  __syncthreads();

  // phase 2: per-row max + unnormalized exp; 8 threads/row, 40 u16 each (cols [0,320))
  {
    const int r = tid >> 3, sg = tid & 7;
    u16* Srow = &S[r * 328 + sg * 40];
    uint4 ch[5];
    float m = -INFINITY;
#pragma unroll
    for (int c = 0; c < 5; c++) {
      ch[c] = *(const uint4*)&Srow[c * 8];
      const u32* w = (const u32*)&ch[c];
#pragma unroll
      for (int d = 0; d < 4; d++) {
        m = fmaxf(m, b2f((u16)(w[d] & 0xffffu)));
        m = fmaxf(m, b2f((u16)(w[d] >> 16)));
      }
    }
    m = fmaxf(m, __shfl_xor(m, 1));
    m = fmaxf(m, __shfl_xor(m, 2));
    m = fmaxf(m, __shfl_xor(m, 4));
    float l = 0.0f;
#pragma unroll
    for (int c = 0; c < 5; c++) {
      u32* w = (u32*)&ch[c];
#pragma unroll
      for (int d = 0; d < 4; d++) {
        const float e0 = __expf(b2f((u16)(w[d] & 0xffffu)) - m);
        const float e1 = __expf(b2f((u16)(w[d] >> 16)) - m);
        l += e0 + e1;
        w[d] = ((u32)f2b(e1) << 16) | f2b(e0);
      }
      *(uint4*)&Srow[c * 8] = ch[c];
    }
    l += __shfl_xor(l, 1);
    l += __shfl_xor(l, 2);
    l += __shfl_xor(l, 4);
    if (sg == 0) Linv[r] = 1.0f / l;
  }
  __syncthreads();

  // phase 3: y = (E @ V^T) * Linv; wave covers hd block = wave*16; 9 static kk chunks
  // (cols >= 288 always masked at QBLK=32); masked chunks contribute exactly 0.
  f32x4 acc[2] = {};
#pragma unroll
  for (int kk = 0; kk < 9; kk++) {
#pragma unroll
    for (int rt = 0; rt < 2; rt++) {
      const bf16x8 pf = *(const bf16x8*)&S[(rt * 16 + ln15) * 328 + kk * 32 + lq * 8];
      __builtin_amdgcn_s_setprio(1);
      acc[rt] = __builtin_amdgcn_mfma_f32_16x16x32_bf16(pf, vf[kk], acc[rt], 0, 0, 0);
      __builtin_amdgcn_s_setprio(0);
    }
  }
#pragma unroll
  for (int rt = 0; rt < 2; rt++)
#pragma unroll
    for (int g2 = 0; g2 < 4; g2++) {
      const int row = rt * 16 + lq * 4 + g2;
      const int i = i0 + row;
      yq[i * NC + h * HDIM + wave * 16 + ln15] = f2b(quantize(acc[rt][g2] * Linv[row]));
    }
}

// ---- proj GEMM: 64x64 tile, BK=64, DEPTH-3 register pipeline (same as k2) ----
__global__ __launch_bounds__(256, 4) void k4_proj(const u16* __restrict__ A,
                                                  const u16* __restrict__ BT,
                                                  float* __restrict__ of) {
  __shared__ __align__(16) u16 As[2][4096];  // [buf][row:64][slot:8][8]
  __shared__ __align__(16) u16 Bs[2][4096];
  const int tid = threadIdx.x;
  const int lane = tid & 63;
  const int wave = tid >> 6;
  const int wr = wave >> 1, wc = wave & 1;
  const int ln15 = lane & 15, lq = lane >> 4;
  const int l7 = ln15 & 7;

  // XCD rectangle partition (bijective: 8 xcd x 8 bx x 8 by = 512 = 16x32)
  const int wg = blockIdx.y * 16 + blockIdx.x;
  const int xcd = wg & 7, t = wg >> 3;    // t in [0,64)
  const int bx = (xcd & 1) * 8 + t % 8;   // [0,16)
  const int by = (xcd >> 1) * 8 + t / 8;  // [0,32)
  const int m0 = by * 64, n0 = bx * 64;

  const int crow = tid >> 3, csl = tid & 7;
  const u16* ag0 = A + (m0 + crow) * NC + csl * 8;
  const u16* bg0 = BT + (n0 + crow) * NC + csl * 8;
  const int wofs = crow * 64 + (csl ^ (crow & 7)) * 8;

  uint4 pa0, pa1, pb0, pb1;  // set P
  uint4 qa0, qa1, qb0, qb1;  // set Q
  f32x4 acc[2][2] = {};

#define K4_LOADP(KT)                               \
  {                                                \
    pa0 = *(const uint4*)(ag0 + (KT));             \
    pa1 = *(const uint4*)(ag0 + 32 * NC + (KT));   \
    pb0 = *(const uint4*)(bg0 + (KT));             \
    pb1 = *(const uint4*)(bg0 + 32 * NC + (KT));   \
  }
#define K4_LOADQ(KT)                               \
  {                                                \
    qa0 = *(const uint4*)(ag0 + (KT));             \
    qa1 = *(const uint4*)(ag0 + 32 * NC + (KT));   \
    qb0 = *(const uint4*)(bg0 + (KT));             \
    qb1 = *(const uint4*)(bg0 + 32 * NC + (KT));   \
  }
#define K4_WRITEP(BUF)                             \
  {                                                \
    *(uint4*)&As[BUF][wofs] = pa0;                 \
    *(uint4*)&As[BUF][wofs + 2048] = pa1;          \
    *(uint4*)&Bs[BUF][wofs] = pb0;                 \
    *(uint4*)&Bs[BUF][wofs + 2048] = pb1;          \
  }
#define K4_WRITEQ(BUF)                             \
  {                                                \
    *(uint4*)&As[BUF][wofs] = qa0;                 \
    *(uint4*)&As[BUF][wofs + 2048] = qa1;          \
    *(uint4*)&Bs[BUF][wofs] = qb0;                 \
    *(uint4*)&Bs[BUF][wofs + 2048] = qb1;          \
  }

  auto compute = [&](const u16* LA, const u16* LB) {
#pragma unroll
    for (int s = 0; s < 2; s++) {
      const int kc = s * 4 + lq;
      const int sw = kc ^ l7;
      bf16x8 af[2], bfr[2];
#pragma unroll
      for (int r = 0; r < 2; r++) {
        const int ar = wr * 32 + r * 16 + ln15;
        af[r] = *(const bf16x8*)&LA[(ar * 8 + sw) * 8];
      }
#pragma unroll
      for (int c = 0; c < 2; c++) {
        const int br = wc * 32 + c * 16 + ln15;
        bfr[c] = *(const bf16x8*)&LB[(br * 8 + sw) * 8];
      }
#pragma unroll
      for (int r = 0; r < 2; r++)
#pragma unroll
        for (int c = 0; c < 2; c++)
          acc[r][c] = __builtin_amdgcn_mfma_f32_16x16x32_bf16(af[r], bfr[c], acc[r][c], 0, 0, 0);
    }
  };

  K4_LOADP(0);
  K4_WRITEP(0);
  K4_LOADQ(64);

  for (int kt = 0; kt < NC; kt += 128) {
    __syncthreads();
    if (kt + 128 < NC) K4_LOADP(kt + 128);
    compute(As[0], Bs[0]);
    K4_WRITEQ(1);
    __syncthreads();
    if (kt + 192 < NC) K4_LOADQ(kt + 192);
    compute(As[1], Bs[1]);
    if (kt + 128 < NC) K4_WRITEP(0);
  }
#undef K4_LOADP
#undef K4_LOADQ
#undef K4_WRITEP
#undef K4_WRITEQ

#pragma unroll
  for (int r = 0; r < 2; r++)
#pragma unroll
    for (int g = 0; g < 4; g++) {
      const int row = m0 + wr * 32 + r * 16 + lq * 4 + g;
#pragma unroll
      for (int c = 0; c < 2; c++)
        of[(long)row * NC + n0 + wc * 32 + c * 16 + ln15] = acc[r][c][g];
    }
}

// ---- launch ----
extern "C" void kernel_launch(void* const* d_in, const int* in_sizes, int n_in,
                              void* d_out, int out_size, void* d_ws, size_t ws_size,
                              hipStream_t stream) {
  // bind by element count (order-robust): x=2M, w_attn=3M, w_proj=1M; dtype fp32
  const void *px = d_in[0], *pwa = d_in[1], *pwp = d_in[2];
  for (int i = 0; i < n_in; i++) {
    if (in_sizes[i] == 2048 * 1024) px = d_in[i];
    else if (in_sizes[i] == 3072 * 1024) pwa = d_in[i];
    else if (in_sizes[i] == 1024 * 1024) pwp = d_in[i];
  }

  char* ws = (char*)d_ws;
  u16* xb  = (u16*)(ws + (1u << 20));    // [2048][1024]  4 MB
  u16* wTa = (u16*)(ws + (5u << 20));    // [3072][1024]  6 MB
  u16* wTp = (u16*)(ws + (11u << 20));   // [1024][1024]  2 MB
  u16* qh  = (u16*)(ws + (13u << 20));   // [16][2048][64] 4 MB
  u16* kh  = (u16*)(ws + (17u << 20));   // 4 MB
  u16* vt  = (u16*)(ws + (21u << 20));   // [16][64][2048] 4 MB
  u16* yq  = (u16*)(ws + (25u << 20));   // [2048][1024]  4 MB

  k1_prep<<<dim3(48, 16, 3), 256, 0, stream>>>((const float*)px, xb, (const float*)pwa, wTa,
                                               (const float*)pwp, wTp);
  k2_qkv<<<dim3(24, 32), 256, 0, stream>>>(xb, wTa, qh, kh, vt);
  k3_attn<<<dim3(64, 16), 256, 0, stream>>>(qh, kh, vt, yq);
  k4_proj<<<dim3(16, 32), 256, 0, stream>>>(yq, wTp, (float*)d_out);
}